// Round 9
// baseline (206.321 us; speedup 1.0000x reference)
//
#include <hip/hip_runtime.h>

#define N_NEURONS 50000
#define N_INPUT   17400
#define NNZ_TOTAL 1000000
#define T_STEPS   256
#define ELL_CAP   64   // rows ~ Poisson(20); P(any row > 64) ~ 3e-9
#define GROUPS    8    // one row-slice per XCD (blockIdx%8 ~ XCD, perf-only)
#define ROWS_PER_GROUP 6250
#define BLKS_PER_GROUP 128

typedef float f4_t __attribute__((ext_vector_type(4)));  // clang-native vec4

// ---------------------------------------------------------------------------
// 1) Tiled transpose + f32->bf16: inp (256 x 17400) -> xTb (17400 x 256) bf16
// ---------------------------------------------------------------------------
__global__ __launch_bounds__(256) void transpose_kernel(
    const float* __restrict__ inp, ushort* __restrict__ xTb) {
    __shared__ float tile[32][33];
    const int bx = blockIdx.x;              // tile along N_INPUT
    const int by = blockIdx.y;              // tile along T
    const int tx = threadIdx.x;             // 0..31
    const int ty = threadIdx.y;             // 0..7

    const int c = bx * 32 + tx;
#pragma unroll
    for (int i = 0; i < 4; ++i) {
        const int r = by * 32 + ty + i * 8;
        if (c < N_INPUT)
            tile[ty + i * 8][tx] = inp[r * N_INPUT + c];
    }
    __syncthreads();

    const int t = by * 32 + tx;
#pragma unroll
    for (int i = 0; i < 4; ++i) {
        const int rr = bx * 32 + ty + i * 8;
        if (rr < N_INPUT) {
            unsigned u = __float_as_uint(tile[tx][ty + i * 8]);
            u += 0x7fffu + ((u >> 16) & 1u);           // RNE to bf16
            xTb[(size_t)rr * T_STEPS + t] = (ushort)(u >> 16);
        }
    }
}

// ---------------------------------------------------------------------------
// 2) ELL build, XCD-partitioned. Group g = blockIdx%8 commits only rows in
//    [g*6250, (g+1)*6250): every ELL/cnt line is touched by ONE XCD, so the
//    1.6 MB per-XCD slice stays L2-resident (kills the 61 MB write-
//    amplification seen in round 7). Each group's 128 blocks partition the
//    nnz stream; rows/cols/w re-reads are L3-served.
//    Entry = (col << 16) | bf16(w). No pre-zeroing needed (spmm masks).
// ---------------------------------------------------------------------------
__global__ __launch_bounds__(256) void ell_build_kernel(
    const int* __restrict__ rows, const int* __restrict__ cols,
    const float* __restrict__ w, int* __restrict__ cnt,
    unsigned* __restrict__ ell) {
    const int g    = blockIdx.x & (GROUPS - 1);
    const int blk  = blockIdx.x >> 3;          // 0..127
    const int r_lo = g * ROWS_PER_GROUP;
    const int r_hi = r_lo + ROWS_PER_GROUP;    // 50000 = 8*6250 exact
    const int per_blk = (NNZ_TOTAL + BLKS_PER_GROUP - 1) / BLKS_PER_GROUP;
    const int i_lo = blk * per_blk;
    const int i_hi = min(i_lo + per_blk, NNZ_TOTAL);

    for (int i = i_lo + (int)threadIdx.x; i < i_hi; i += 256) {
        const int r = rows[i];                 // coalesced 4B/lane
        if (r >= r_lo && r < r_hi) {           // ~1/8 of lanes
            const int p = atomicAdd(&cnt[r], 1);   // XCD-local L2 RMW
            if (p < ELL_CAP) {                 // safety clamp (never hit)
                unsigned u = __float_as_uint(w[i]);
                u += 0x7fffu + ((u >> 16) & 1u);   // RNE to bf16
                ell[(size_t)r * ELL_CAP + p] =
                    ((unsigned)cols[i] << 16) | (u >> 16);
            }
        }
    }
}

// ---------------------------------------------------------------------------
// 3) Main SpMM: block = 256 = 4 waves; wave owns 4 neurons; lane holds
//    float4 acc for t = lane*4..+3. Row metadata = one 4B/lane coalesced
//    load (invalid lanes zeroed in-register: w=+0, col=0 -> harmless).
//    k-loop over count padded to multiple of 8, unrolled x8 -> 8 gathers
//    in flight per wave.
// ---------------------------------------------------------------------------
__global__ __launch_bounds__(256) void spmm_kernel(
    const uint2* __restrict__ xT2,            // bf16 [N_INPUT][64] uint2
    const int* __restrict__ cnt, const unsigned* __restrict__ ell,
    const float* __restrict__ bkg, float* __restrict__ out) {
    __shared__ float lds[16][260];
    const int tid  = threadIdx.x;
    const int lane = tid & 63;
    const int wv   = tid >> 6;                // 0..3
    const int base = blockIdx.x * 16;         // 50000 = 3125 * 16
    const int n0   = base + wv * 4;

    const int4   cv  = *(const int4*)&cnt[n0];
    const float4 bgv = *(const float4*)&bkg[n0];
    const int cs[4] = {min(cv.x, ELL_CAP), min(cv.y, ELL_CAP),
                       min(cv.z, ELL_CAP), min(cv.w, ELL_CAP)};
    unsigned ev[4];
#pragma unroll
    for (int q = 0; q < 4; ++q) {
        const unsigned raw = ell[(size_t)(n0 + q) * ELL_CAP + lane];
        ev[q] = (lane < cs[q]) ? raw : 0u;    // mask garbage (no ELL memset)
    }

#pragma unroll
    for (int q = 0; q < 4; ++q) {
        const int cpad = (cs[q] + 7) & ~7;    // <= 64
        float4 acc = make_float4(0.f, 0.f, 0.f, 0.f);

        for (int k0 = 0; k0 < cpad; k0 += 8) {
            unsigned e[8];
            uint2 xv[8];
#pragma unroll
            for (int j = 0; j < 8; ++j) e[j] = __shfl(ev[q], k0 + j);
#pragma unroll
            for (int j = 0; j < 8; ++j)
                xv[j] = xT2[(size_t)(e[j] >> 16) * 64 + lane]; // 8 in flight
#pragma unroll
            for (int j = 0; j < 8; ++j) {
                const float wk = __uint_as_float(e[j] << 16);  // bf16 -> f32
                acc.x = fmaf(wk, __uint_as_float((xv[j].x & 0xffffu) << 16), acc.x);
                acc.y = fmaf(wk, __uint_as_float(xv[j].x & 0xffff0000u),     acc.y);
                acc.z = fmaf(wk, __uint_as_float((xv[j].y & 0xffffu) << 16), acc.z);
                acc.w = fmaf(wk, __uint_as_float(xv[j].y & 0xffff0000u),     acc.w);
            }
        }
        const float b4 = 4.0f * ((q == 0) ? bgv.x : (q == 1) ? bgv.y
                                 : (q == 2) ? bgv.z : bgv.w);
        acc.x += b4; acc.y += b4; acc.z += b4; acc.w += b4;
        *(float4*)&lds[wv * 4 + q][lane * 4] = acc;
    }
    __syncthreads();

    // out is (256, 50000); 64B contiguous segments per 4-lane group.
    // Non-temporal: write-once stream must not evict the xT gather set.
    const int c4 = (tid & 3) * 4;
    const int t0 = tid >> 2;                  // 0..63
#pragma unroll
    for (int t = t0; t < T_STEPS; t += 64) {
        f4_t v;
        v.x = lds[c4 + 0][t];
        v.y = lds[c4 + 1][t];
        v.z = lds[c4 + 2][t];
        v.w = lds[c4 + 3][t];
        __builtin_nontemporal_store(
            v, (f4_t*)&out[(size_t)t * N_NEURONS + base + c4]);
    }
}

// ---------------------------------------------------------------------------
extern "C" void kernel_launch(void* const* d_in, const int* in_sizes, int n_in,
                              void* d_out, int out_size, void* d_ws,
                              size_t ws_size, hipStream_t stream) {
    const float* inp     = (const float*)d_in[0];  // (1, 256, 17400) f32
    const float* weights = (const float*)d_in[1];  // (1e6,) f32
    const float* bkg     = (const float*)d_in[2];  // (50000,) f32
    const int*   rows    = (const int*)d_in[3];    // (1e6,) i32
    const int*   cols    = (const int*)d_in[4];    // (1e6,) i32
    float*       out     = (float*)d_out;          // (1, 256, 50000) f32

    size_t off = 0;
    auto wsalloc = [&](size_t bytes) -> void* {
        void* p = (char*)d_ws + off;
        off += (bytes + 255) & ~size_t(255);
        return p;
    };
    ushort*   xTb = (ushort*)wsalloc(sizeof(ushort) * N_INPUT * T_STEPS); // 8.9MB
    int*      cnt = (int*)wsalloc(sizeof(int) * N_NEURONS);               // 200KB
    unsigned* ell = (unsigned*)wsalloc(sizeof(unsigned) * N_NEURONS * ELL_CAP); // 12.8MB
    (void)ws_size;  // ~22 MB total

    // Only cnt needs zeroing now (spmm masks unwritten ELL slots).
    (void)hipMemsetAsync(cnt, 0, sizeof(int) * N_NEURONS, stream);

    transpose_kernel<<<dim3((N_INPUT + 31) / 32, T_STEPS / 32), dim3(32, 8), 0,
                       stream>>>(inp, xTb);

    ell_build_kernel<<<GROUPS * BLKS_PER_GROUP, 256, 0, stream>>>(
        rows, cols, weights, cnt, ell);

    spmm_kernel<<<N_NEURONS / 16, 256, 0, stream>>>(
        (const uint2*)xTb, cnt, ell, bkg, out);
}

// Round 10
// 197.714 us; speedup vs baseline: 1.0435x; 1.0435x over previous
//
#include <hip/hip_runtime.h>

#define N_NEURONS 50000
#define N_INPUT   17400
#define NNZ_TOTAL 1000000
#define T_STEPS   256
#define ELL_CAP   64   // rows ~ Poisson(20); P(any row > 64) ~ 3e-9
#define GROUPS    8    // one row-slice per XCD (blockIdx%8 ~ XCD, perf-only)
#define ROWS_PER_GROUP 6250
#define BLKS_PER_GROUP 256

typedef float f4_t __attribute__((ext_vector_type(4)));  // clang-native vec4

// ---------------------------------------------------------------------------
// 1) Tiled transpose + f32->bf16: inp (256 x 17400) -> xTb (17400 x 256) bf16
// ---------------------------------------------------------------------------
__global__ __launch_bounds__(256) void transpose_kernel(
    const float* __restrict__ inp, ushort* __restrict__ xTb) {
    __shared__ float tile[32][33];
    const int bx = blockIdx.x;              // tile along N_INPUT
    const int by = blockIdx.y;              // tile along T
    const int tx = threadIdx.x;             // 0..31
    const int ty = threadIdx.y;             // 0..7

    const int c = bx * 32 + tx;
#pragma unroll
    for (int i = 0; i < 4; ++i) {
        const int r = by * 32 + ty + i * 8;
        if (c < N_INPUT)
            tile[ty + i * 8][tx] = inp[r * N_INPUT + c];
    }
    __syncthreads();

    const int t = by * 32 + tx;
#pragma unroll
    for (int i = 0; i < 4; ++i) {
        const int rr = bx * 32 + ty + i * 8;
        if (rr < N_INPUT) {
            unsigned u = __float_as_uint(tile[tx][ty + i * 8]);
            u += 0x7fffu + ((u >> 16) & 1u);           // RNE to bf16
            xTb[(size_t)rr * T_STEPS + t] = (ushort)(u >> 16);
        }
    }
}

// ---------------------------------------------------------------------------
// 2) ELL build, XCD-partitioned + NON-TEMPORAL streams. Group g = blockIdx%8
//    commits only rows in [g*6250,(g+1)*6250). Key fix vs round 9: the
//    streaming reads of rows/cols/w are non-temporal so they cannot thrash
//    the hot RMW working set (cnt slice + ELL slice, ~1.8 MB/XCD) out of the
//    XCD-private L2 — dirty ELL lines stay resident until final writeback.
//    Entry = (col << 16) | bf16(w). No pre-zeroing needed (spmm masks).
// ---------------------------------------------------------------------------
__global__ __launch_bounds__(256) void ell_build_kernel(
    const int* __restrict__ rows, const int* __restrict__ cols,
    const float* __restrict__ w, int* __restrict__ cnt,
    unsigned* __restrict__ ell) {
    const int g    = blockIdx.x & (GROUPS - 1);
    const int blk  = blockIdx.x >> 3;          // 0..255
    const int r_lo = g * ROWS_PER_GROUP;
    const int r_hi = r_lo + ROWS_PER_GROUP;    // 50000 = 8*6250 exact
    const int per_blk = (NNZ_TOTAL + BLKS_PER_GROUP - 1) / BLKS_PER_GROUP;
    const int i_lo = blk * per_blk;
    const int i_hi = min(i_lo + per_blk, NNZ_TOTAL);

#pragma unroll 4
    for (int i = i_lo + (int)threadIdx.x; i < i_hi; i += 256) {
        const int r = __builtin_nontemporal_load(&rows[i]);    // NT stream
        // Unconditional coalesced NT loads; pack entry before the branch.
        const unsigned c = (unsigned)__builtin_nontemporal_load(&cols[i]);
        unsigned u = __float_as_uint(__builtin_nontemporal_load(&w[i]));
        u += 0x7fffu + ((u >> 16) & 1u);       // RNE to bf16
        const unsigned entry = (c << 16) | (u >> 16);
        if (r >= r_lo && r < r_hi) {           // ~1/8 of lanes commit
            const int p = atomicAdd(&cnt[r], 1);   // XCD-local L2 RMW
            if (p < ELL_CAP)                   // safety clamp (never hit)
                ell[(size_t)r * ELL_CAP + p] = entry;
        }
    }
}

// ---------------------------------------------------------------------------
// 3) Main SpMM: block = 256 = 4 waves; wave owns 4 neurons; lane holds
//    float4 acc for t = lane*4..+3. Row metadata = one 4B/lane coalesced
//    NT load (read-once; keeps xTb gather set in L2), invalid lanes zeroed
//    in-register. k-loop padded to multiple of 8, unrolled x8 -> 8 gathers
//    in flight per wave.
// ---------------------------------------------------------------------------
__global__ __launch_bounds__(256) void spmm_kernel(
    const uint2* __restrict__ xT2,            // bf16 [N_INPUT][64] uint2
    const int* __restrict__ cnt, const unsigned* __restrict__ ell,
    const float* __restrict__ bkg, float* __restrict__ out) {
    __shared__ float lds[16][260];
    const int tid  = threadIdx.x;
    const int lane = tid & 63;
    const int wv   = tid >> 6;                // 0..3
    const int base = blockIdx.x * 16;         // 50000 = 3125 * 16
    const int n0   = base + wv * 4;

    const int4   cv  = *(const int4*)&cnt[n0];
    const float4 bgv = *(const float4*)&bkg[n0];
    const int cs[4] = {min(cv.x, ELL_CAP), min(cv.y, ELL_CAP),
                       min(cv.z, ELL_CAP), min(cv.w, ELL_CAP)};
    unsigned ev[4];
#pragma unroll
    for (int q = 0; q < 4; ++q) {
        const unsigned raw =
            __builtin_nontemporal_load(&ell[(size_t)(n0 + q) * ELL_CAP + lane]);
        ev[q] = (lane < cs[q]) ? raw : 0u;    // mask garbage (no ELL memset)
    }

#pragma unroll
    for (int q = 0; q < 4; ++q) {
        const int cpad = (cs[q] + 7) & ~7;    // <= 64
        float4 acc = make_float4(0.f, 0.f, 0.f, 0.f);

        for (int k0 = 0; k0 < cpad; k0 += 8) {
            unsigned e[8];
            uint2 xv[8];
#pragma unroll
            for (int j = 0; j < 8; ++j) e[j] = __shfl(ev[q], k0 + j);
#pragma unroll
            for (int j = 0; j < 8; ++j)
                xv[j] = xT2[(size_t)(e[j] >> 16) * 64 + lane]; // 8 in flight
#pragma unroll
            for (int j = 0; j < 8; ++j) {
                const float wk = __uint_as_float(e[j] << 16);  // bf16 -> f32
                acc.x = fmaf(wk, __uint_as_float((xv[j].x & 0xffffu) << 16), acc.x);
                acc.y = fmaf(wk, __uint_as_float(xv[j].x & 0xffff0000u),     acc.y);
                acc.z = fmaf(wk, __uint_as_float((xv[j].y & 0xffffu) << 16), acc.z);
                acc.w = fmaf(wk, __uint_as_float(xv[j].y & 0xffff0000u),     acc.w);
            }
        }
        const float b4 = 4.0f * ((q == 0) ? bgv.x : (q == 1) ? bgv.y
                                 : (q == 2) ? bgv.z : bgv.w);
        acc.x += b4; acc.y += b4; acc.z += b4; acc.w += b4;
        *(float4*)&lds[wv * 4 + q][lane * 4] = acc;
    }
    __syncthreads();

    // out is (256, 50000); 64B contiguous segments per 4-lane group.
    // Non-temporal: write-once stream must not evict the xT gather set.
    const int c4 = (tid & 3) * 4;
    const int t0 = tid >> 2;                  // 0..63
#pragma unroll
    for (int t = t0; t < T_STEPS; t += 64) {
        f4_t v;
        v.x = lds[c4 + 0][t];
        v.y = lds[c4 + 1][t];
        v.z = lds[c4 + 2][t];
        v.w = lds[c4 + 3][t];
        __builtin_nontemporal_store(
            v, (f4_t*)&out[(size_t)t * N_NEURONS + base + c4]);
    }
}

// ---------------------------------------------------------------------------
extern "C" void kernel_launch(void* const* d_in, const int* in_sizes, int n_in,
                              void* d_out, int out_size, void* d_ws,
                              size_t ws_size, hipStream_t stream) {
    const float* inp     = (const float*)d_in[0];  // (1, 256, 17400) f32
    const float* weights = (const float*)d_in[1];  // (1e6,) f32
    const float* bkg     = (const float*)d_in[2];  // (50000,) f32
    const int*   rows    = (const int*)d_in[3];    // (1e6,) i32
    const int*   cols    = (const int*)d_in[4];    // (1e6,) i32
    float*       out     = (float*)d_out;          // (1, 256, 50000) f32

    size_t off = 0;
    auto wsalloc = [&](size_t bytes) -> void* {
        void* p = (char*)d_ws + off;
        off += (bytes + 255) & ~size_t(255);
        return p;
    };
    ushort*   xTb = (ushort*)wsalloc(sizeof(ushort) * N_INPUT * T_STEPS); // 8.9MB
    int*      cnt = (int*)wsalloc(sizeof(int) * N_NEURONS);               // 200KB
    unsigned* ell = (unsigned*)wsalloc(sizeof(unsigned) * N_NEURONS * ELL_CAP); // 12.8MB
    (void)ws_size;  // ~22 MB total

    // Only cnt needs zeroing (spmm masks unwritten ELL slots).
    (void)hipMemsetAsync(cnt, 0, sizeof(int) * N_NEURONS, stream);

    transpose_kernel<<<dim3((N_INPUT + 31) / 32, T_STEPS / 32), dim3(32, 8), 0,
                       stream>>>(inp, xTb);

    ell_build_kernel<<<GROUPS * BLKS_PER_GROUP, 256, 0, stream>>>(
        rows, cols, weights, cnt, ell);

    spmm_kernel<<<N_NEURONS / 16, 256, 0, stream>>>(
        (const uint2*)xTb, cnt, ell, bkg, out);
}

// Round 12
// 197.138 us; speedup vs baseline: 1.0466x; 1.0029x over previous
//
#include <hip/hip_runtime.h>

#define N_NEURONS 50000
#define N_INPUT   17400
#define NNZ_TOTAL 1000000
#define T_STEPS   256
#define ELL_CAP   64   // rows ~ Poisson(20); P(any row > 64) ~ 3e-9
#define GROUPS    8    // one row-slice per XCD (blockIdx%8 ~ XCD, perf-only)
#define ROWS_PER_GROUP 6250
#define BLKS_PER_GROUP 256
#define PER_BLK   3908 // ceil(1e6/256) rounded up to a multiple of 4

typedef float f4_t  __attribute__((ext_vector_type(4)));  // clang-native vec4
typedef int   i4_t  __attribute__((ext_vector_type(4)));

// ---------------------------------------------------------------------------
// 1) Tiled transpose + f32->bf16: inp (256 x 17400) -> xTb (17400 x 256) bf16
// ---------------------------------------------------------------------------
__global__ __launch_bounds__(256) void transpose_kernel(
    const float* __restrict__ inp, ushort* __restrict__ xTb) {
    __shared__ float tile[32][33];
    const int bx = blockIdx.x;              // tile along N_INPUT
    const int by = blockIdx.y;              // tile along T
    const int tx = threadIdx.x;             // 0..31
    const int ty = threadIdx.y;             // 0..7

    const int c = bx * 32 + tx;
#pragma unroll
    for (int i = 0; i < 4; ++i) {
        const int r = by * 32 + ty + i * 8;
        if (c < N_INPUT)
            tile[ty + i * 8][tx] = inp[r * N_INPUT + c];
    }
    __syncthreads();

    const int t = by * 32 + tx;
#pragma unroll
    for (int i = 0; i < 4; ++i) {
        const int rr = bx * 32 + ty + i * 8;
        if (rr < N_INPUT) {
            unsigned u = __float_as_uint(tile[tx][ty + i * 8]);
            u += 0x7fffu + ((u >> 16) & 1u);           // RNE to bf16
            xTb[(size_t)rr * T_STEPS + t] = (ushort)(u >> 16);
        }
    }
}

// ---------------------------------------------------------------------------
// 2) ELL build, XCD-partitioned + NT vec4 streams. Group g = blockIdx%8
//    commits only rows in [g*6250,(g+1)*6250): ELL/cnt lines stay XCD-local.
//    rows/cols/w are read as 16B/lane non-temporal vectors (no L2 thrash,
//    4x fewer loop trips than scalar). Entry = (col<<16) | bf16(w).
//    No ELL pre-zeroing needed (spmm masks unwritten slots).
// ---------------------------------------------------------------------------
__global__ __launch_bounds__(256) void ell_build_kernel(
    const int* __restrict__ rows, const int* __restrict__ cols,
    const float* __restrict__ w, int* __restrict__ cnt,
    unsigned* __restrict__ ell) {
    const int g    = blockIdx.x & (GROUPS - 1);
    const int blk  = blockIdx.x >> 3;          // 0..255
    const int r_lo = g * ROWS_PER_GROUP;
    const int r_hi = r_lo + ROWS_PER_GROUP;    // 50000 = 8*6250 exact
    const int i_lo = blk * PER_BLK;
    const int i_hi = min(i_lo + PER_BLK, NNZ_TOTAL);
    // i_lo/i_hi and the stride are multiples of 4 -> vec4 accesses stay
    // in-bounds and aligned (1e6 % 4 == 0, PER_BLK % 4 == 0).

    for (int i = i_lo + (int)threadIdx.x * 4; i < i_hi; i += 256 * 4) {
        const i4_t r4 = __builtin_nontemporal_load((const i4_t*)&rows[i]);
        const i4_t c4 = __builtin_nontemporal_load((const i4_t*)&cols[i]);
        const f4_t w4 = __builtin_nontemporal_load((const f4_t*)&w[i]);
#pragma unroll
        for (int e = 0; e < 4; ++e) {
            const int r = r4[e];
            if (r >= r_lo && r < r_hi) {       // ~1/8 of elements commit
                unsigned u = __float_as_uint(w4[e]);
                u += 0x7fffu + ((u >> 16) & 1u);   // RNE to bf16
                const unsigned entry = ((unsigned)c4[e] << 16) | (u >> 16);
                const int p = atomicAdd(&cnt[r], 1);   // XCD-local L2 RMW
                if (p < ELL_CAP)               // safety clamp (never hit)
                    ell[(size_t)r * ELL_CAP + p] = entry;
            }
        }
    }
}

// ---------------------------------------------------------------------------
// 3) Main SpMM: block = 256 = 4 waves; wave owns 4 neurons; lane holds
//    float4 acc for t = lane*4..+3. Rows are processed in PAIRS with a
//    shared padded trip count (ev zero-masked, so the shorter row's extra
//    entries are zero-FMAs): 16 independent gathers in flight per wave to
//    hide the ~300cy L2/L3 gather latency (round 10 showed 8 wasn't enough:
//    VALUBusy 35%, latency-bound).
// ---------------------------------------------------------------------------
__global__ __launch_bounds__(256) void spmm_kernel(
    const uint2* __restrict__ xT2,            // bf16 [N_INPUT][64] uint2
    const int* __restrict__ cnt, const unsigned* __restrict__ ell,
    const float* __restrict__ bkg, float* __restrict__ out) {
    __shared__ float lds[16][260];
    const int tid  = threadIdx.x;
    const int lane = tid & 63;
    const int wv   = tid >> 6;                // 0..3
    const int base = blockIdx.x * 16;         // 50000 = 3125 * 16
    const int n0   = base + wv * 4;

    const int4   cv  = *(const int4*)&cnt[n0];
    const float4 bgv = *(const float4*)&bkg[n0];
    const int cs[4] = {min(cv.x, ELL_CAP), min(cv.y, ELL_CAP),
                       min(cv.z, ELL_CAP), min(cv.w, ELL_CAP)};
    const float bg[4] = {bgv.x, bgv.y, bgv.z, bgv.w};
    unsigned ev[4];
#pragma unroll
    for (int q = 0; q < 4; ++q) {
        const unsigned raw =
            __builtin_nontemporal_load(&ell[(size_t)(n0 + q) * ELL_CAP + lane]);
        ev[q] = (lane < cs[q]) ? raw : 0u;    // mask garbage (no ELL memset)
    }

#pragma unroll
    for (int qq = 0; qq < 4; qq += 2) {
        const int cpad = (max(cs[qq], cs[qq + 1]) + 7) & ~7;  // <= 64
        float4 accA = make_float4(0.f, 0.f, 0.f, 0.f);
        float4 accB = make_float4(0.f, 0.f, 0.f, 0.f);

        for (int k0 = 0; k0 < cpad; k0 += 8) {
            unsigned eA[8], eB[8];
            uint2 xvA[8], xvB[8];
#pragma unroll
            for (int j = 0; j < 8; ++j) {
                eA[j] = __shfl(ev[qq],     k0 + j);
                eB[j] = __shfl(ev[qq + 1], k0 + j);
            }
#pragma unroll
            for (int j = 0; j < 8; ++j)
                xvA[j] = xT2[(size_t)(eA[j] >> 16) * 64 + lane];
#pragma unroll
            for (int j = 0; j < 8; ++j)
                xvB[j] = xT2[(size_t)(eB[j] >> 16) * 64 + lane];
#pragma unroll
            for (int j = 0; j < 8; ++j) {
                const float wk = __uint_as_float(eA[j] << 16);
                accA.x = fmaf(wk, __uint_as_float((xvA[j].x & 0xffffu) << 16), accA.x);
                accA.y = fmaf(wk, __uint_as_float(xvA[j].x & 0xffff0000u),     accA.y);
                accA.z = fmaf(wk, __uint_as_float((xvA[j].y & 0xffffu) << 16), accA.z);
                accA.w = fmaf(wk, __uint_as_float(xvA[j].y & 0xffff0000u),     accA.w);
            }
#pragma unroll
            for (int j = 0; j < 8; ++j) {
                const float wk = __uint_as_float(eB[j] << 16);
                accB.x = fmaf(wk, __uint_as_float((xvB[j].x & 0xffffu) << 16), accB.x);
                accB.y = fmaf(wk, __uint_as_float(xvB[j].x & 0xffff0000u),     accB.y);
                accB.z = fmaf(wk, __uint_as_float((xvB[j].y & 0xffffu) << 16), accB.z);
                accB.w = fmaf(wk, __uint_as_float(xvB[j].y & 0xffff0000u),     accB.w);
            }
        }
        const float bA = 4.0f * bg[qq];
        const float bB = 4.0f * bg[qq + 1];
        accA.x += bA; accA.y += bA; accA.z += bA; accA.w += bA;
        accB.x += bB; accB.y += bB; accB.z += bB; accB.w += bB;
        *(float4*)&lds[wv * 4 + qq][lane * 4]     = accA;
        *(float4*)&lds[wv * 4 + qq + 1][lane * 4] = accB;
    }
    __syncthreads();

    // out is (256, 50000); 64B contiguous segments per 4-lane group.
    // Non-temporal: write-once stream must not evict the xT gather set.
    const int c4 = (tid & 3) * 4;
    const int t0 = tid >> 2;                  // 0..63
#pragma unroll
    for (int t = t0; t < T_STEPS; t += 64) {
        f4_t v;
        v.x = lds[c4 + 0][t];
        v.y = lds[c4 + 1][t];
        v.z = lds[c4 + 2][t];
        v.w = lds[c4 + 3][t];
        __builtin_nontemporal_store(
            v, (f4_t*)&out[(size_t)t * N_NEURONS + base + c4]);
    }
}

// ---------------------------------------------------------------------------
extern "C" void kernel_launch(void* const* d_in, const int* in_sizes, int n_in,
                              void* d_out, int out_size, void* d_ws,
                              size_t ws_size, hipStream_t stream) {
    const float* inp     = (const float*)d_in[0];  // (1, 256, 17400) f32
    const float* weights = (const float*)d_in[1];  // (1e6,) f32
    const float* bkg     = (const float*)d_in[2];  // (50000,) f32
    const int*   rows    = (const int*)d_in[3];    // (1e6,) i32
    const int*   cols    = (const int*)d_in[4];    // (1e6,) i32
    float*       out     = (float*)d_out;          // (1, 256, 50000) f32

    size_t off = 0;
    auto wsalloc = [&](size_t bytes) -> void* {
        void* p = (char*)d_ws + off;
        off += (bytes + 255) & ~size_t(255);
        return p;
    };
    ushort*   xTb = (ushort*)wsalloc(sizeof(ushort) * N_INPUT * T_STEPS); // 8.9MB
    int*      cnt = (int*)wsalloc(sizeof(int) * N_NEURONS);               // 200KB
    unsigned* ell = (unsigned*)wsalloc(sizeof(unsigned) * N_NEURONS * ELL_CAP); // 12.8MB
    (void)ws_size;  // ~22 MB total

    // Only cnt needs zeroing (spmm masks unwritten ELL slots).
    (void)hipMemsetAsync(cnt, 0, sizeof(int) * N_NEURONS, stream);

    transpose_kernel<<<dim3((N_INPUT + 31) / 32, T_STEPS / 32), dim3(32, 8), 0,
                       stream>>>(inp, xTb);

    ell_build_kernel<<<GROUPS * BLKS_PER_GROUP, 256, 0, stream>>>(
        rows, cols, weights, cnt, ell);

    spmm_kernel<<<N_NEURONS / 16, 256, 0, stream>>>(
        (const uint2*)xTb, cnt, ell, bkg, out);
}

// Round 14
// 196.762 us; speedup vs baseline: 1.0486x; 1.0019x over previous
//
#include <hip/hip_runtime.h>

#define N_NEURONS 50000
#define N_INPUT   17400
#define NNZ_TOTAL 1000000
#define T_STEPS   256
#define ELL_CAP   64   // rows ~ Poisson(20); P(any row > 64) ~ 3e-9
#define GROUPS    8    // one row-slice per XCD (blockIdx%8 ~ XCD, perf-only)
#define ROWS_PER_GROUP 6250
#define ELL_BLOCKS 2048            // 8 groups x 256 blocks
#define PER_BLK   3908             // ceil(1e6/256) rounded to mult of 4
#define TP_TILES_X 544             // ceil(17400/32)
#define TP_BLOCKS (TP_TILES_X * 8) // 4352

typedef float f4_t  __attribute__((ext_vector_type(4)));  // clang-native vec4
typedef int   i4_t  __attribute__((ext_vector_type(4)));

// ---------------------------------------------------------------------------
// 1) Fused prep: ELL build (blocks 0..2047) + transpose (blocks 2048..6399).
//    The two parts touch disjoint outputs; fusing saves a launch and overlaps
//    the latency-bound build with the BW-bound transpose. ELL first (longer).
// ---------------------------------------------------------------------------
__global__ __launch_bounds__(256) void prep_kernel(
    const float* __restrict__ inp, ushort* __restrict__ xTb,
    const int* __restrict__ rows, const int* __restrict__ cols,
    const float* __restrict__ w, int* __restrict__ cnt,
    unsigned* __restrict__ ell) {
    __shared__ float tile[32][33];
    const int bid = blockIdx.x;

    if (bid < ELL_BLOCKS) {
        // ---- ELL build, XCD-partitioned + NT vec4 streams ----
        const int g    = bid & (GROUPS - 1);
        const int blk  = bid >> 3;             // 0..255
        const int r_lo = g * ROWS_PER_GROUP;
        const int r_hi = r_lo + ROWS_PER_GROUP;
        const int i_lo = blk * PER_BLK;
        const int i_hi = min(i_lo + PER_BLK, NNZ_TOTAL);
        for (int i = i_lo + (int)threadIdx.x * 4; i < i_hi; i += 256 * 4) {
            const i4_t r4 = __builtin_nontemporal_load((const i4_t*)&rows[i]);
            const i4_t c4 = __builtin_nontemporal_load((const i4_t*)&cols[i]);
            const f4_t w4 = __builtin_nontemporal_load((const f4_t*)&w[i]);
#pragma unroll
            for (int e = 0; e < 4; ++e) {
                const int r = r4[e];
                if (r >= r_lo && r < r_hi) {   // ~1/8 of elements commit
                    unsigned u = __float_as_uint(w4[e]);
                    u += 0x7fffu + ((u >> 16) & 1u);   // RNE to bf16
                    const unsigned entry = ((unsigned)c4[e] << 16) | (u >> 16);
                    const int p = atomicAdd(&cnt[r], 1);   // XCD-local RMW
                    if (p < ELL_CAP)           // safety clamp (never hit)
                        ell[(size_t)r * ELL_CAP + p] = entry;
                }
            }
        }
    } else {
        // ---- tiled transpose + f32->bf16 ----
        const int tb = bid - ELL_BLOCKS;
        const int bx = tb % TP_TILES_X;        // tile along N_INPUT
        const int by = tb / TP_TILES_X;        // 0..7 along T
        const int tx = (int)threadIdx.x & 31;
        const int ty = (int)threadIdx.x >> 5;  // 0..7
        const int c = bx * 32 + tx;
#pragma unroll
        for (int i = 0; i < 4; ++i) {
            const int r = by * 32 + ty + i * 8;
            if (c < N_INPUT)
                tile[ty + i * 8][tx] = inp[r * N_INPUT + c];
        }
        __syncthreads();
        const int t = by * 32 + tx;
#pragma unroll
        for (int i = 0; i < 4; ++i) {
            const int rr = bx * 32 + ty + i * 8;
            if (rr < N_INPUT) {
                unsigned u = __float_as_uint(tile[tx][ty + i * 8]);
                u += 0x7fffu + ((u >> 16) & 1u);       // RNE to bf16
                xTb[(size_t)rr * T_STEPS + t] = (ushort)(u >> 16);
            }
        }
    }
}

// ---------------------------------------------------------------------------
// 2) Main SpMM: block = 256 = 4 waves; wave owns 4 neurons (2 pairs); lane
//    holds float4 acc for t = lane*4..+3. Explicit 2-buffer software
//    pipeline — batch k+1's 16 gathers are issued BEFORE batch k's FMAs, so
//    the ~400-600cy gather latency hides under ~256cy of FMA instead of
//    stalling every batch (rounds 10/12 showed within-batch ILP alone is not
//    enough). Buffers hold only the gathered x-values; weights re-__shfl'd
//    at FMA time to keep VGPR moderate.
// ---------------------------------------------------------------------------
__global__ __launch_bounds__(256) void spmm_kernel(
    const uint2* __restrict__ xT2,            // bf16 [N_INPUT][64] uint2
    const int* __restrict__ cnt, const unsigned* __restrict__ ell,
    const float* __restrict__ bkg, float* __restrict__ out) {
    __shared__ float lds[16][260];
    const int tid  = threadIdx.x;
    const int lane = tid & 63;
    const int wv   = tid >> 6;                // 0..3
    const int base = blockIdx.x * 16;         // 50000 = 3125 * 16
    const int n0   = base + wv * 4;

    const int4   cv  = *(const int4*)&cnt[n0];
    const float4 bgv = *(const float4*)&bkg[n0];
    const int cs[4] = {min(cv.x, ELL_CAP), min(cv.y, ELL_CAP),
                       min(cv.z, ELL_CAP), min(cv.w, ELL_CAP)};
    const float bg[4] = {bgv.x, bgv.y, bgv.z, bgv.w};
    unsigned ev[4];
#pragma unroll
    for (int q = 0; q < 4; ++q) {
        const unsigned raw =
            __builtin_nontemporal_load(&ell[(size_t)(n0 + q) * ELL_CAP + lane]);
        ev[q] = (lane < cs[q]) ? raw : 0u;    // mask garbage (no ELL memset)
    }

#pragma unroll
    for (int qq = 0; qq < 4; qq += 2) {
        const unsigned ev0 = ev[qq];
        const unsigned ev1 = ev[qq + 1];
        const int cpad = (max(cs[qq], cs[qq + 1]) + 7) & ~7;  // <= 64
        float4 accA = make_float4(0.f, 0.f, 0.f, 0.f);
        float4 accB = make_float4(0.f, 0.f, 0.f, 0.f);

        uint2 xa0[8], xb0[8], xa1[8], xb1[8]; // static-indexed (regs only)

#define LOADB(XA, XB, K)                                                    \
        {                                                                   \
            _Pragma("unroll")                                               \
            for (int j = 0; j < 8; ++j) {                                   \
                const unsigned eA = __shfl(ev0, (K) + j);                   \
                const unsigned eB = __shfl(ev1, (K) + j);                   \
                XA[j] = xT2[(size_t)(eA >> 16) * 64 + lane];                \
                XB[j] = xT2[(size_t)(eB >> 16) * 64 + lane];                \
            }                                                               \
        }

#define FMAB(XA, XB, K)                                                     \
        {                                                                   \
            _Pragma("unroll")                                               \
            for (int j = 0; j < 8; ++j) {                                   \
                const float wA = __uint_as_float(__shfl(ev0, (K) + j) << 16); \
                accA.x = fmaf(wA, __uint_as_float((XA[j].x & 0xffffu) << 16), accA.x); \
                accA.y = fmaf(wA, __uint_as_float(XA[j].x & 0xffff0000u),     accA.y); \
                accA.z = fmaf(wA, __uint_as_float((XA[j].y & 0xffffu) << 16), accA.z); \
                accA.w = fmaf(wA, __uint_as_float(XA[j].y & 0xffff0000u),     accA.w); \
                const float wB = __uint_as_float(__shfl(ev1, (K) + j) << 16); \
                accB.x = fmaf(wB, __uint_as_float((XB[j].x & 0xffffu) << 16), accB.x); \
                accB.y = fmaf(wB, __uint_as_float(XB[j].x & 0xffff0000u),     accB.y); \
                accB.z = fmaf(wB, __uint_as_float((XB[j].y & 0xffffu) << 16), accB.z); \
                accB.w = fmaf(wB, __uint_as_float(XB[j].y & 0xffff0000u),     accB.w); \
            }                                                               \
        }

        LOADB(xa0, xb0, 0);                   // prologue: batch 0 in flight
        int k = 0;
        while (k + 16 <= cpad) {              // uniform per wave: no diverge
            LOADB(xa1, xb1, k + 8);           // prefetch next batch
            FMAB(xa0, xb0, k);                // consume current
            if (k + 16 < cpad) LOADB(xa0, xb0, k + 16);
            FMAB(xa1, xb1, k + 8);
            k += 16;
        }
        if (k < cpad) FMAB(xa0, xb0, k);      // odd-batch tail

#undef LOADB
#undef FMAB

        const float bA = 4.0f * bg[qq];
        const float bB = 4.0f * bg[qq + 1];
        accA.x += bA; accA.y += bA; accA.z += bA; accA.w += bA;
        accB.x += bB; accB.y += bB; accB.z += bB; accB.w += bB;
        *(float4*)&lds[wv * 4 + qq][lane * 4]     = accA;
        *(float4*)&lds[wv * 4 + qq + 1][lane * 4] = accB;
    }
    __syncthreads();

    // out is (256, 50000); 64B contiguous segments per 4-lane group.
    // Non-temporal: write-once stream must not evict the xT gather set.
    const int c4 = (tid & 3) * 4;
    const int t0 = tid >> 2;                  // 0..63
#pragma unroll
    for (int t = t0; t < T_STEPS; t += 64) {
        f4_t v;
        v.x = lds[c4 + 0][t];
        v.y = lds[c4 + 1][t];
        v.z = lds[c4 + 2][t];
        v.w = lds[c4 + 3][t];
        __builtin_nontemporal_store(
            v, (f4_t*)&out[(size_t)t * N_NEURONS + base + c4]);
    }
}

// ---------------------------------------------------------------------------
extern "C" void kernel_launch(void* const* d_in, const int* in_sizes, int n_in,
                              void* d_out, int out_size, void* d_ws,
                              size_t ws_size, hipStream_t stream) {
    const float* inp     = (const float*)d_in[0];  // (1, 256, 17400) f32
    const float* weights = (const float*)d_in[1];  // (1e6,) f32
    const float* bkg     = (const float*)d_in[2];  // (50000,) f32
    const int*   rows    = (const int*)d_in[3];    // (1e6,) i32
    const int*   cols    = (const int*)d_in[4];    // (1e6,) i32
    float*       out     = (float*)d_out;          // (1, 256, 50000) f32

    size_t off = 0;
    auto wsalloc = [&](size_t bytes) -> void* {
        void* p = (char*)d_ws + off;
        off += (bytes + 255) & ~size_t(255);
        return p;
    };
    ushort*   xTb = (ushort*)wsalloc(sizeof(ushort) * N_INPUT * T_STEPS); // 8.9MB
    int*      cnt = (int*)wsalloc(sizeof(int) * N_NEURONS);               // 200KB
    unsigned* ell = (unsigned*)wsalloc(sizeof(unsigned) * N_NEURONS * ELL_CAP); // 12.8MB
    (void)ws_size;  // ~22 MB total

    // Only cnt needs zeroing (spmm masks unwritten ELL slots).
    (void)hipMemsetAsync(cnt, 0, sizeof(int) * N_NEURONS, stream);

    prep_kernel<<<ELL_BLOCKS + TP_BLOCKS, 256, 0, stream>>>(
        inp, xTb, rows, cols, weights, cnt, ell);

    spmm_kernel<<<N_NEURONS / 16, 256, 0, stream>>>(
        (const uint2*)xTb, cnt, ell, bkg, out);
}